// Round 2
// baseline (694.139 us; speedup 1.0000x reference)
//
#include <hip/hip_runtime.h>

#define SEQ    2048
#define DIM    2048              // D == N
#define NBATCH 4
#define MTOT   (NBATCH * SEQ)    // 8192
#define CHUNKS 32
#define CLEN   (SEQ / CHUNKS)    // 64
#define NBM    (MTOT / 128)      // 64

typedef __bf16 bf16_t;
typedef __bf16 bf16x8 __attribute__((ext_vector_type(8)));
typedef float  f32x4  __attribute__((ext_vector_type(4)));
typedef unsigned short u16x4 __attribute__((ext_vector_type(4)));

__device__ __forceinline__ unsigned short f2bf_rne(float f) {
    unsigned int u = __float_as_uint(f);
    u += 0x7fffu + ((u >> 16) & 1u);
    return (unsigned short)(u >> 16);
}

// ---------------- fp32 -> bf16 convert ----------------
__global__ void k_convert(const float* __restrict__ src,
                          unsigned short* __restrict__ dst, int n4) {
    int i = blockIdx.x * blockDim.x + threadIdx.x;
    if (i >= n4) return;
    f32x4 v = ((const f32x4*)src)[i];
    u16x4 o;
    o[0] = f2bf_rne(v[0]); o[1] = f2bf_rne(v[1]);
    o[2] = f2bf_rne(v[2]); o[3] = f2bf_rne(v[3]);
    ((u16x4*)dst)[i] = o;
}

// convert + interleave: src row n -> dst row 2n+phase (dst has 2*rows rows)
__global__ void k_convert_ilv(const float* __restrict__ src,
                              unsigned short* __restrict__ dst, int n4, int phase) {
    int i = blockIdx.x * blockDim.x + threadIdx.x;
    if (i >= n4) return;
    const int R4 = DIM / 4;            // 512 vec4 per row
    int nrow = i / R4;
    int dcol = i - nrow * R4;
    f32x4 v = ((const f32x4*)src)[i];
    u16x4 o;
    o[0] = f2bf_rne(v[0]); o[1] = f2bf_rne(v[1]);
    o[2] = f2bf_rne(v[2]); o[3] = f2bf_rne(v[3]);
    ((u16x4*)dst)[(2 * nrow + phase) * R4 + dcol] = o;
}

// ---------------- shared GEMM core (128x128 tile, dbuf LDS, XOR swizzle) ----
// LDS physical layout: tile row r (64B of bf16, BK=32) stored as 4 chunks of
// 16B; physical chunk pc holds logical chunk g = pc ^ ((r>>1)&3).
__device__ __forceinline__ void stage_tile(const bf16_t* __restrict__ g, long rowbase,
                                           int K, int k0, bf16_t* lds,
                                           int wave, int lane) {
    const int rl     = lane >> 2;                       // 0..15 row within slab
    const int gchunk = (lane & 3) ^ ((lane >> 3) & 3);  // swizzled global chunk
#pragma unroll
    for (int q = 0; q < 2; q++) {
        const bf16_t* ga = g + (rowbase + wave * 32 + q * 16 + rl) * (long)K
                             + k0 + gchunk * 8;
        __builtin_amdgcn_global_load_lds(
            (const __attribute__((address_space(1))) void*)ga,
            (__attribute__((address_space(3))) void*)((char*)lds + (wave * 32 + q * 16) * 64),
            16, 0, 0);
    }
}

__device__ __forceinline__ void gemm_main(const bf16_t* __restrict__ A,
                                          const bf16_t* __restrict__ Bm,
                                          int K, long arow0, long brow0,
                                          bf16_t* As, bf16_t* Bs,  // each 2*128*32
                                          f32x4 acc[4][4],
                                          int wave, int lane, int wm, int wn) {
    const int l15  = lane & 15;
    const int quad = lane >> 4;
    const int swz  = (quad ^ ((l15 >> 1) & 3)) * 8;   // physical chunk offset (elems)

    stage_tile(A,  arow0, K, 0, As, wave, lane);
    stage_tile(Bm, brow0, K, 0, Bs, wave, lane);
    __syncthreads();
    int cur = 0;
    for (int k0 = 32;; k0 += 32) {
        if (k0 < K) {
            int nxt = cur ^ 1;
            stage_tile(A,  arow0, K, k0, As + nxt * (128 * 32), wave, lane);
            stage_tile(Bm, brow0, K, k0, Bs + nxt * (128 * 32), wave, lane);
        }
        const bf16_t* ap = As + cur * (128 * 32);
        const bf16_t* bp = Bs + cur * (128 * 32);
        bf16x8 af[4], bfr[4];
#pragma unroll
        for (int i = 0; i < 4; i++) {
            af[i]  = *(const bf16x8*)(ap + (wm * 64 + i * 16 + l15) * 32 + swz);
            bfr[i] = *(const bf16x8*)(bp + (wn * 64 + i * 16 + l15) * 32 + swz);
        }
#pragma unroll
        for (int i = 0; i < 4; i++)
#pragma unroll
            for (int j = 0; j < 4; j++)
                acc[i][j] = __builtin_amdgcn_mfma_f32_16x16x32_bf16(
                    af[i], bfr[j], acc[i][j], 0, 0, 0);
        if (k0 >= K) break;
        __syncthreads();   // drains prefetch (vmcnt) + guards cur-buffer reuse
        cur ^= 1;
    }
}

// ---------------- fused GEMM1+2 + elementwise epilogue ----------------
// Wcat row 2n = W_dt[n,:], row 2n+1 = W_B[n,:]. N = 4096.
__global__ __launch_bounds__(256)
void k_gemm_fused(const bf16_t* __restrict__ A, const bf16_t* __restrict__ Wcat,
                  const float* __restrict__ x, const float* __restrict__ b_dt,
                  const float* __restrict__ A_log,
                  float* __restrict__ abuf, float* __restrict__ ubuf) {
    __shared__ __align__(16) bf16_t As[2 * 128 * 32];
    __shared__ __align__(16) bf16_t Bs[2 * 128 * 32];

    const int tid  = threadIdx.x;
    const int lane = tid & 63;
    const int wave = tid >> 6;
    const int wm   = wave >> 1;
    const int wn   = wave & 1;
    int flat = blockIdx.y * gridDim.x + blockIdx.x;
    int bm = flat % NBM;            // consecutive blocks share bn -> B-tile L2-hot
    int bn = flat / NBM;

    f32x4 acc[4][4];
#pragma unroll
    for (int i = 0; i < 4; i++)
#pragma unroll
        for (int j = 0; j < 4; j++) acc[i][j] = (f32x4){0.f, 0.f, 0.f, 0.f};

    gemm_main(A, Wcat, DIM, (long)bm * 128, (long)bn * 128, As, Bs, acc, wave, lane, wm, wn);

    const int l15  = lane & 15;
    const int quad = lane >> 4;
    const int odd  = l15 & 1;
#pragma unroll
    for (int i = 0; i < 4; i++) {
#pragma unroll
        for (int j = 0; j < 4; j++) {
#pragma unroll
            for (int r = 0; r < 4; r++) {
                float v = acc[i][j][r];
                float w = __shfl_xor(v, 1);
                float dtpre = odd ? w : v;
                float bpv   = odd ? v : w;
                long row = (long)bm * 128 + wm * 64 + i * 16 + quad * 4 + r;
                int  col = bn * 128 + wn * 64 + j * 16 + l15;
                int  n   = col >> 1;
                float z  = dtpre + b_dt[n];
                float dt = (z > 15.f) ? z : log1pf(__expf(z));   // softplus
                float a  = __expf(-__expf(A_log[n]) * dt);       // A_bar
                float u  = dt * bpv * x[row * DIM + n];          // dt*Bp*x
                long idx = row * DIM + n;
                if (odd) ubuf[idx] = u; else abuf[idx] = a;
            }
        }
    }
}

// ---------------- plain NT-GEMM (for out = h * W_C^T + skip*x) ----------------
__global__ __launch_bounds__(256)
void k_gemm_bt(const bf16_t* __restrict__ A, const bf16_t* __restrict__ Bm,
               float* __restrict__ C, int N, int K,
               const float* __restrict__ skip, const float* __restrict__ xres) {
    __shared__ __align__(16) bf16_t As[2 * 128 * 32];
    __shared__ __align__(16) bf16_t Bs[2 * 128 * 32];

    const int tid  = threadIdx.x;
    const int lane = tid & 63;
    const int wave = tid >> 6;
    const int wm   = wave >> 1;
    const int wn   = wave & 1;
    int flat = blockIdx.y * gridDim.x + blockIdx.x;
    int bm = flat % NBM;
    int bn = flat / NBM;

    f32x4 acc[4][4];
#pragma unroll
    for (int i = 0; i < 4; i++)
#pragma unroll
        for (int j = 0; j < 4; j++) acc[i][j] = (f32x4){0.f, 0.f, 0.f, 0.f};

    gemm_main(A, Bm, K, (long)bm * 128, (long)bn * 128, As, Bs, acc, wave, lane, wm, wn);

    const int l15  = lane & 15;
    const int quad = lane >> 4;
#pragma unroll
    for (int i = 0; i < 4; i++) {
#pragma unroll
        for (int j = 0; j < 4; j++) {
#pragma unroll
            for (int r = 0; r < 4; r++) {
                long row = (long)bm * 128 + wm * 64 + i * 16 + quad * 4 + r;
                long col = (long)bn * 128 + wn * 64 + j * 16 + l15;
                long idx = row * (long)N + col;
                float v = acc[i][j][r];
                if (skip) v += skip[col] * xres[idx];
                C[idx] = v;
            }
        }
    }
}

// ---------------- chunked scan: h_t = a_t*h_{t-1} + u_t ----------------
__global__ void k_scan1(const float* __restrict__ a, const float* __restrict__ u,
                        float* __restrict__ P, float* __restrict__ V) {
    int t = blockIdx.x * blockDim.x + threadIdx.x;   // [b][c][n]
    int n = t & (DIM - 1);
    int c = (t >> 11) & (CHUNKS - 1);
    int b = t >> 16;
    long base = ((long)b * SEQ + (long)c * CLEN) * DIM + n;
    float p = 1.f, v = 0.f;
    for (int s = 0; s < CLEN; s++) {
        float av = a[base + (long)s * DIM];
        float uv = u[base + (long)s * DIM];
        v = av * v + uv;
        p *= av;
    }
    P[t] = p; V[t] = v;
}

__global__ void k_scan2(const float* __restrict__ P, const float* __restrict__ V,
                        float* __restrict__ carry) {
    int t = blockIdx.x * blockDim.x + threadIdx.x;   // B*N
    int n = t & (DIM - 1);
    int b = t >> 11;
    float H = 0.f;
    for (int c = 0; c < CHUNKS; c++) {
        long idx = ((long)b * CHUNKS + c) * DIM + n;
        carry[idx] = H;
        H = P[idx] * H + V[idx];
    }
}

__global__ void k_scan3(const float* __restrict__ a, const float* __restrict__ u,
                        const float* __restrict__ carry,
                        unsigned short* __restrict__ h) {
    int t = blockIdx.x * blockDim.x + threadIdx.x;
    int n = t & (DIM - 1);
    int c = (t >> 11) & (CHUNKS - 1);
    int b = t >> 16;
    long base = ((long)b * SEQ + (long)c * CLEN) * DIM + n;
    float H = carry[t];
    for (int s = 0; s < CLEN; s++) {
        float av = a[base + (long)s * DIM];
        float uv = u[base + (long)s * DIM];
        H = av * H + uv;
        h[base + (long)s * DIM] = f2bf_rne(H);
    }
}

extern "C" void kernel_launch(void* const* d_in, const int* in_sizes, int n_in,
                              void* d_out, int out_size, void* d_ws, size_t ws_size,
                              hipStream_t stream) {
    const float* x      = (const float*)d_in[0];
    const float* W_dt   = (const float*)d_in[1];
    const float* b_dt   = (const float*)d_in[2];
    const float* W_B    = (const float*)d_in[3];
    const float* W_C    = (const float*)d_in[4];
    const float* A_log  = (const float*)d_in[5];
    const float* D_skip = (const float*)d_in[6];
    float* out = (float*)d_out;

    char* ws = (char*)d_ws;
    size_t off = 0;
    auto alloc = [&](size_t bytes) -> char* {
        char* p = ws + off;
        off += (bytes + 255) & ~(size_t)255;
        return p;
    };
    unsigned short* xb   = (unsigned short*)alloc((size_t)MTOT * DIM * 2); // reused as h_bf
    unsigned short* wcat = (unsigned short*)alloc((size_t)2 * DIM * DIM * 2);
    unsigned short* wcb  = (unsigned short*)alloc((size_t)DIM * DIM * 2);
    float* abuf  = (float*)alloc((size_t)MTOT * DIM * 4);  // a = exp(dt*A)
    float* ubuf  = (float*)alloc((size_t)MTOT * DIM * 4);  // u = dt*Bp*x
    float* P     = (float*)alloc((size_t)NBATCH * CHUNKS * DIM * 4);
    float* V     = (float*)alloc((size_t)NBATCH * CHUNKS * DIM * 4);
    float* carry = (float*)alloc((size_t)NBATCH * CHUNKS * DIM * 4);

    const int n4x = MTOT * DIM / 4;
    const int n4w = DIM * DIM / 4;
    k_convert<<<n4x / 256, 256, 0, stream>>>(x, xb, n4x);
    k_convert_ilv<<<n4w / 256, 256, 0, stream>>>(W_dt, wcat, n4w, 0);
    k_convert_ilv<<<n4w / 256, 256, 0, stream>>>(W_B,  wcat, n4w, 1);
    k_convert<<<n4w / 256, 256, 0, stream>>>(W_C, wcb, n4w);

    // fused GEMM1+2 + elementwise: M=8192, N=4096, K=2048
    dim3 fgrid(2 * DIM / 128, MTOT / 128);   // (32, 64) -> 2048 blocks
    k_gemm_fused<<<fgrid, 256, 0, stream>>>((const bf16_t*)xb, (const bf16_t*)wcat,
                                            x, b_dt, A_log, abuf, ubuf);

    const int scan_threads = NBATCH * CHUNKS * DIM;
    k_scan1<<<scan_threads / 256, 256, 0, stream>>>(abuf, ubuf, P, V);
    k_scan2<<<(NBATCH * DIM) / 256, 256, 0, stream>>>(P, V, carry);
    k_scan3<<<scan_threads / 256, 256, 0, stream>>>(abuf, ubuf, carry, xb /* h_bf */);

    // out = h * W_C^T + D_skip * x : M=8192, N=2048, K=2048
    dim3 ggrid(DIM / 128, MTOT / 128);       // (16, 64)
    k_gemm_bt<<<ggrid, 256, 0, stream>>>((const bf16_t*)xb, (const bf16_t*)wcb,
                                         out, DIM, DIM, D_skip, x);
}

// Round 3
// 604.723 us; speedup vs baseline: 1.1479x; 1.1479x over previous
//
#include <hip/hip_runtime.h>

#define SEQ    2048
#define DIM    2048              // D == N
#define NBATCH 4
#define MTOT   (NBATCH * SEQ)    // 8192
#define CHUNKS 32
#define CLEN   (SEQ / CHUNKS)    // 64
#define NBM    (MTOT / 128)      // 64
#define TILE_E (128 * 32)        // elems per LDS tile (128 rows x BK=32)

typedef __bf16 bf16_t;
typedef __bf16 bf16x8 __attribute__((ext_vector_type(8)));
typedef float  f32x4  __attribute__((ext_vector_type(4)));
typedef unsigned short u16x4 __attribute__((ext_vector_type(4)));

__device__ __forceinline__ unsigned short f2bf_rne(float f) {
    unsigned int u = __float_as_uint(f);
    u += 0x7fffu + ((u >> 16) & 1u);
    return (unsigned short)(u >> 16);
}

// ---------------- fp32 -> bf16 convert ----------------
__global__ void k_convert(const float* __restrict__ src,
                          unsigned short* __restrict__ dst, int n4) {
    int i = blockIdx.x * blockDim.x + threadIdx.x;
    if (i >= n4) return;
    f32x4 v = ((const f32x4*)src)[i];
    u16x4 o;
    o[0] = f2bf_rne(v[0]); o[1] = f2bf_rne(v[1]);
    o[2] = f2bf_rne(v[2]); o[3] = f2bf_rne(v[3]);
    ((u16x4*)dst)[i] = o;
}

// convert + interleave: src row n -> dst row 2n+phase
__global__ void k_convert_ilv(const float* __restrict__ src,
                              unsigned short* __restrict__ dst, int n4, int phase) {
    int i = blockIdx.x * blockDim.x + threadIdx.x;
    if (i >= n4) return;
    const int R4 = DIM / 4;
    int nrow = i / R4;
    int dcol = i - nrow * R4;
    f32x4 v = ((const f32x4*)src)[i];
    u16x4 o;
    o[0] = f2bf_rne(v[0]); o[1] = f2bf_rne(v[1]);
    o[2] = f2bf_rne(v[2]); o[3] = f2bf_rne(v[3]);
    ((u16x4*)dst)[(2 * nrow + phase) * R4 + dcol] = o;
}

// negA[n] = -exp(A_log[n])
__global__ void k_prep_a(const float* __restrict__ A_log, float* __restrict__ negA, int n) {
    int i = blockIdx.x * blockDim.x + threadIdx.x;
    if (i < n) negA[i] = -__expf(A_log[i]);
}

// ---------------- staging: 4 global_load_lds (16B) per wave per tile-pair half
// LDS row r (64B): physical chunk pc holds logical chunk pc ^ ((r>>1)&3).
__device__ __forceinline__ void stage_tile(const bf16_t* __restrict__ g, long rowbase,
                                           int K, int k0, bf16_t* lds,
                                           int wave, int lane) {
    const int rl     = lane >> 2;
    const int gchunk = (lane & 3) ^ ((lane >> 3) & 3);
#pragma unroll
    for (int q = 0; q < 2; q++) {
        const bf16_t* ga = g + (rowbase + wave * 32 + q * 16 + rl) * (long)K
                             + k0 + gchunk * 8;
        __builtin_amdgcn_global_load_lds(
            (const __attribute__((address_space(1))) void*)ga,
            (__attribute__((address_space(3))) void*)((char*)lds + (wave * 32 + q * 16) * 64),
            16, 0, 0);
    }
}

// ---------------- GEMM core: 128x128 tile, triple-buffer LDS, distance-2
// prefetch, raw s_barrier with fine-grained vmcnt (never 0 until tail).
template <int KITERS>
__device__ __forceinline__ void gemm_main(const bf16_t* __restrict__ A,
                                          const bf16_t* __restrict__ Bm,
                                          int K, long arow0, long brow0,
                                          bf16_t* As, bf16_t* Bs,  // each 3*TILE_E
                                          f32x4 acc[4][4],
                                          int wave, int lane, int wm, int wn) {
    const int l15  = lane & 15;
    const int quad = lane >> 4;
    const int swz  = (quad ^ ((l15 >> 1) & 3)) * 8;

    // prologue: stage iters 0 and 1
    stage_tile(A,  arow0, K, 0,  As,          wave, lane);
    stage_tile(Bm, brow0, K, 0,  Bs,          wave, lane);
    stage_tile(A,  arow0, K, 32, As + TILE_E, wave, lane);
    stage_tile(Bm, brow0, K, 32, Bs + TILE_E, wave, lane);

    int cur = 0;
    for (int i = 0; i < KITERS - 1; ++i) {
        // wait for stage i (leaving stage i+1's 4 loads in flight), then barrier
        asm volatile("s_waitcnt vmcnt(4)\n\ts_barrier" ::: "memory");
        const bf16_t* ap = As + cur * TILE_E;
        const bf16_t* bp = Bs + cur * TILE_E;
        bf16x8 af[4], bfr[4];
#pragma unroll
        for (int t = 0; t < 4; t++) {
            af[t]  = *(const bf16x8*)(ap + (wm * 64 + t * 16 + l15) * 32 + swz);
            bfr[t] = *(const bf16x8*)(bp + (wn * 64 + t * 16 + l15) * 32 + swz);
        }
        if (i + 2 < KITERS) {           // prefetch stage i+2 (after barrier -> safe)
            int nxt = cur + 2; if (nxt >= 3) nxt -= 3;
            stage_tile(A,  arow0, K, (i + 2) * 32, As + nxt * TILE_E, wave, lane);
            stage_tile(Bm, brow0, K, (i + 2) * 32, Bs + nxt * TILE_E, wave, lane);
        }
#pragma unroll
        for (int t = 0; t < 4; t++)
#pragma unroll
            for (int j = 0; j < 4; j++)
                acc[t][j] = __builtin_amdgcn_mfma_f32_16x16x32_bf16(
                    af[t], bfr[j], acc[t][j], 0, 0, 0);
        cur += 1; if (cur == 3) cur = 0;
    }
    // final iteration: nothing left in flight after this wait
    asm volatile("s_waitcnt vmcnt(0)\n\ts_barrier" ::: "memory");
    const bf16_t* ap = As + cur * TILE_E;
    const bf16_t* bp = Bs + cur * TILE_E;
    bf16x8 af[4], bfr[4];
#pragma unroll
    for (int t = 0; t < 4; t++) {
        af[t]  = *(const bf16x8*)(ap + (wm * 64 + t * 16 + l15) * 32 + swz);
        bfr[t] = *(const bf16x8*)(bp + (wn * 64 + t * 16 + l15) * 32 + swz);
    }
#pragma unroll
    for (int t = 0; t < 4; t++)
#pragma unroll
        for (int j = 0; j < 4; j++)
            acc[t][j] = __builtin_amdgcn_mfma_f32_16x16x32_bf16(
                af[t], bfr[j], acc[t][j], 0, 0, 0);
}

// ---------------- fused GEMM1+2 + elementwise epilogue ----------------
__global__ __launch_bounds__(256)
void k_gemm_fused(const bf16_t* __restrict__ A, const bf16_t* __restrict__ Wcat,
                  const float* __restrict__ x, const float* __restrict__ b_dt,
                  const float* __restrict__ negA,
                  float* __restrict__ abuf, float* __restrict__ ubuf) {
    __shared__ __align__(16) bf16_t As[3 * TILE_E];
    __shared__ __align__(16) bf16_t Bs[3 * TILE_E];

    const int tid  = threadIdx.x;
    const int lane = tid & 63;
    const int wave = tid >> 6;
    const int wm   = wave >> 1;
    const int wn   = wave & 1;
    int flat = blockIdx.y * gridDim.x + blockIdx.x;
    int bm = flat % NBM;            // consecutive blocks share bn -> B tile L2-hot
    int bn = flat / NBM;

    f32x4 acc[4][4];
#pragma unroll
    for (int i = 0; i < 4; i++)
#pragma unroll
        for (int j = 0; j < 4; j++) acc[i][j] = (f32x4){0.f, 0.f, 0.f, 0.f};

    gemm_main<DIM / 32>(A, Wcat, DIM, (long)bm * 128, (long)bn * 128,
                        As, Bs, acc, wave, lane, wm, wn);

    const int l15  = lane & 15;
    const int quad = lane >> 4;
    const int odd  = l15 & 1;
#pragma unroll
    for (int i = 0; i < 4; i++) {
#pragma unroll
        for (int j = 0; j < 4; j++) {
#pragma unroll
            for (int r = 0; r < 4; r++) {
                float v = acc[i][j][r];
                float w = __shfl_xor(v, 1);
                float dtpre = odd ? w : v;
                float bpv   = odd ? v : w;
                long row = (long)bm * 128 + wm * 64 + i * 16 + quad * 4 + r;
                int  col = bn * 128 + wn * 64 + j * 16 + l15;
                int  n   = col >> 1;
                float z  = dtpre + b_dt[n];
                float dt = (z > 15.f) ? z : __logf(1.f + __expf(z)); // softplus
                float a  = __expf(negA[n] * dt);                     // A_bar
                float u  = dt * bpv * x[row * DIM + n];              // dt*Bp*x
                long idx = row * DIM + n;
                if (odd) ubuf[idx] = u; else abuf[idx] = a;
            }
        }
    }
}

// ---------------- plain NT-GEMM: out = h*W_C^T + skip*x ----------------
__global__ __launch_bounds__(256)
void k_gemm_bt(const bf16_t* __restrict__ A, const bf16_t* __restrict__ Bm,
               float* __restrict__ C, int N, int K,
               const float* __restrict__ skip, const float* __restrict__ xres) {
    __shared__ __align__(16) bf16_t As[3 * TILE_E];
    __shared__ __align__(16) bf16_t Bs[3 * TILE_E];

    const int tid  = threadIdx.x;
    const int lane = tid & 63;
    const int wave = tid >> 6;
    const int wm   = wave >> 1;
    const int wn   = wave & 1;
    int flat = blockIdx.y * gridDim.x + blockIdx.x;
    int bm = flat % NBM;
    int bn = flat / NBM;

    f32x4 acc[4][4];
#pragma unroll
    for (int i = 0; i < 4; i++)
#pragma unroll
        for (int j = 0; j < 4; j++) acc[i][j] = (f32x4){0.f, 0.f, 0.f, 0.f};

    gemm_main<DIM / 32>(A, Bm, K, (long)bm * 128, (long)bn * 128,
                        As, Bs, acc, wave, lane, wm, wn);

    const int l15  = lane & 15;
    const int quad = lane >> 4;
#pragma unroll
    for (int i = 0; i < 4; i++) {
#pragma unroll
        for (int j = 0; j < 4; j++) {
#pragma unroll
            for (int r = 0; r < 4; r++) {
                long row = (long)bm * 128 + wm * 64 + i * 16 + quad * 4 + r;
                long col = (long)bn * 128 + wn * 64 + j * 16 + l15;
                long idx = row * (long)N + col;
                float v = acc[i][j][r];
                if (skip) v += skip[col] * xres[idx];
                C[idx] = v;
            }
        }
    }
}

// ---------------- chunked scan: h_t = a_t*h_{t-1} + u_t ----------------
__global__ void k_scan1(const float* __restrict__ a, const float* __restrict__ u,
                        float* __restrict__ P, float* __restrict__ V) {
    int t = blockIdx.x * blockDim.x + threadIdx.x;
    int n = t & (DIM - 1);
    int c = (t >> 11) & (CHUNKS - 1);
    int b = t >> 16;
    long base = ((long)b * SEQ + (long)c * CLEN) * DIM + n;
    float p = 1.f, v = 0.f;
    for (int s = 0; s < CLEN; s++) {
        float av = a[base + (long)s * DIM];
        float uv = u[base + (long)s * DIM];
        v = av * v + uv;
        p *= av;
    }
    P[t] = p; V[t] = v;
}

__global__ void k_scan2(const float* __restrict__ P, const float* __restrict__ V,
                        float* __restrict__ carry) {
    int t = blockIdx.x * blockDim.x + threadIdx.x;
    int n = t & (DIM - 1);
    int b = t >> 11;
    float H = 0.f;
    for (int c = 0; c < CHUNKS; c++) {
        long idx = ((long)b * CHUNKS + c) * DIM + n;
        carry[idx] = H;
        H = P[idx] * H + V[idx];
    }
}

__global__ void k_scan3(const float* __restrict__ a, const float* __restrict__ u,
                        const float* __restrict__ carry,
                        unsigned short* __restrict__ h) {
    int t = blockIdx.x * blockDim.x + threadIdx.x;
    int n = t & (DIM - 1);
    int c = (t >> 11) & (CHUNKS - 1);
    int b = t >> 16;
    long base = ((long)b * SEQ + (long)c * CLEN) * DIM + n;
    float H = carry[t];
    for (int s = 0; s < CLEN; s++) {
        float av = a[base + (long)s * DIM];
        float uv = u[base + (long)s * DIM];
        H = av * H + uv;
        h[base + (long)s * DIM] = f2bf_rne(H);
    }
}

extern "C" void kernel_launch(void* const* d_in, const int* in_sizes, int n_in,
                              void* d_out, int out_size, void* d_ws, size_t ws_size,
                              hipStream_t stream) {
    const float* x      = (const float*)d_in[0];
    const float* W_dt   = (const float*)d_in[1];
    const float* b_dt   = (const float*)d_in[2];
    const float* W_B    = (const float*)d_in[3];
    const float* W_C    = (const float*)d_in[4];
    const float* A_log  = (const float*)d_in[5];
    const float* D_skip = (const float*)d_in[6];
    float* out = (float*)d_out;

    char* ws = (char*)d_ws;
    size_t off = 0;
    auto alloc = [&](size_t bytes) -> char* {
        char* p = ws + off;
        off += (bytes + 255) & ~(size_t)255;
        return p;
    };
    unsigned short* xb   = (unsigned short*)alloc((size_t)MTOT * DIM * 2); // reused as h_bf
    unsigned short* wcat = (unsigned short*)alloc((size_t)2 * DIM * DIM * 2);
    unsigned short* wcb  = (unsigned short*)alloc((size_t)DIM * DIM * 2);
    float* abuf  = (float*)alloc((size_t)MTOT * DIM * 4);
    float* ubuf  = (float*)alloc((size_t)MTOT * DIM * 4);
    float* P     = (float*)alloc((size_t)NBATCH * CHUNKS * DIM * 4);
    float* V     = (float*)alloc((size_t)NBATCH * CHUNKS * DIM * 4);
    float* carry = (float*)alloc((size_t)NBATCH * CHUNKS * DIM * 4);
    float* negA  = (float*)alloc((size_t)DIM * 4);

    const int n4x = MTOT * DIM / 4;
    const int n4w = DIM * DIM / 4;
    k_convert<<<n4x / 256, 256, 0, stream>>>(x, xb, n4x);
    k_convert_ilv<<<n4w / 256, 256, 0, stream>>>(W_dt, wcat, n4w, 0);
    k_convert_ilv<<<n4w / 256, 256, 0, stream>>>(W_B,  wcat, n4w, 1);
    k_convert<<<n4w / 256, 256, 0, stream>>>(W_C, wcb, n4w);
    k_prep_a<<<DIM / 256, 256, 0, stream>>>(A_log, negA, DIM);

    // fused GEMM1+2 + elementwise: M=8192, N=4096, K=2048
    dim3 fgrid(2 * DIM / 128, MTOT / 128);
    k_gemm_fused<<<fgrid, 256, 0, stream>>>((const bf16_t*)xb, (const bf16_t*)wcat,
                                            x, b_dt, negA, abuf, ubuf);

    const int scan_threads = NBATCH * CHUNKS * DIM;
    k_scan1<<<scan_threads / 256, 256, 0, stream>>>(abuf, ubuf, P, V);
    k_scan2<<<(NBATCH * DIM) / 256, 256, 0, stream>>>(P, V, carry);
    k_scan3<<<scan_threads / 256, 256, 0, stream>>>(abuf, ubuf, carry, xb /* h_bf */);

    // out = h * W_C^T + D_skip * x
    dim3 ggrid(DIM / 128, MTOT / 128);
    k_gemm_bt<<<ggrid, 256, 0, stream>>>((const bf16_t*)xb, (const bf16_t*)wcb,
                                         out, DIM, DIM, D_skip, x);
}

// Round 4
// 561.652 us; speedup vs baseline: 1.2359x; 1.0767x over previous
//
#include <hip/hip_runtime.h>

#define SEQ    2048
#define DIM    2048              // D == N
#define NBATCH 4
#define MTOT   (NBATCH * SEQ)    // 8192
#define CHUNKS 32
#define CLEN   (SEQ / CHUNKS)    // 64
#define NBM    (MTOT / 128)      // 64
#define TILE_E (128 * 32)        // elems per LDS tile (128 rows x BK=32)

typedef __bf16 bf16_t;
typedef __bf16 bf16x8 __attribute__((ext_vector_type(8)));
typedef float  f32x4  __attribute__((ext_vector_type(4)));
typedef unsigned short u16x4 __attribute__((ext_vector_type(4)));
typedef unsigned short u16x2 __attribute__((ext_vector_type(2)));

__device__ __forceinline__ unsigned short f2bf_rne(float f) {
    unsigned int u = __float_as_uint(f);
    u += 0x7fffu + ((u >> 16) & 1u);
    return (unsigned short)(u >> 16);
}
__device__ __forceinline__ float bf2f(unsigned short v) {
    return __uint_as_float((unsigned int)v << 16);
}

// ---------------- fp32 -> bf16 convert ----------------
__global__ void k_convert(const float* __restrict__ src,
                          unsigned short* __restrict__ dst, int n4) {
    int i = blockIdx.x * blockDim.x + threadIdx.x;
    if (i >= n4) return;
    f32x4 v = ((const f32x4*)src)[i];
    u16x4 o;
    o[0] = f2bf_rne(v[0]); o[1] = f2bf_rne(v[1]);
    o[2] = f2bf_rne(v[2]); o[3] = f2bf_rne(v[3]);
    ((u16x4*)dst)[i] = o;
}

// convert + interleave: src row n -> dst row 2n+phase
__global__ void k_convert_ilv(const float* __restrict__ src,
                              unsigned short* __restrict__ dst, int n4, int phase) {
    int i = blockIdx.x * blockDim.x + threadIdx.x;
    if (i >= n4) return;
    const int R4 = DIM / 4;
    int nrow = i / R4;
    int dcol = i - nrow * R4;
    f32x4 v = ((const f32x4*)src)[i];
    u16x4 o;
    o[0] = f2bf_rne(v[0]); o[1] = f2bf_rne(v[1]);
    o[2] = f2bf_rne(v[2]); o[3] = f2bf_rne(v[3]);
    ((u16x4*)dst)[(2 * nrow + phase) * R4 + dcol] = o;
}

// negA[n] = -exp(A_log[n])
__global__ void k_prep_a(const float* __restrict__ A_log, float* __restrict__ negA, int n) {
    int i = blockIdx.x * blockDim.x + threadIdx.x;
    if (i < n) negA[i] = -__expf(A_log[i]);
}

// ---------------- staging: 16B global_load_lds, XOR-swizzled chunks ----------
// LDS row r (64B): physical chunk pc holds logical chunk pc ^ ((r>>1)&3).
__device__ __forceinline__ void stage_tile(const bf16_t* __restrict__ g, long rowbase,
                                           int K, int k0, bf16_t* lds,
                                           int wave, int lane) {
    const int rl     = lane >> 2;
    const int gchunk = (lane & 3) ^ ((lane >> 3) & 3);
#pragma unroll
    for (int q = 0; q < 2; q++) {
        const bf16_t* ga = g + (rowbase + wave * 32 + q * 16 + rl) * (long)K
                             + k0 + gchunk * 8;
        __builtin_amdgcn_global_load_lds(
            (const __attribute__((address_space(1))) void*)ga,
            (__attribute__((address_space(3))) void*)((char*)lds + (wave * 32 + q * 16) * 64),
            16, 0, 0);
    }
}

// ---------------- GEMM core: 128x128 tile, DOUBLE-buffer LDS (32 KB ->
// 5 blocks/CU), distance-1 prefetch, one raw s_barrier per iter.
template <int KITERS>
__device__ __forceinline__ void gemm_main(const bf16_t* __restrict__ A,
                                          const bf16_t* __restrict__ Bm,
                                          int K, long arow0, long brow0,
                                          bf16_t* As, bf16_t* Bs,  // each 2*TILE_E
                                          f32x4 acc[4][4],
                                          int wave, int lane, int wm, int wn) {
    const int l15  = lane & 15;
    const int quad = lane >> 4;
    const int swz  = (quad ^ ((l15 >> 1) & 3)) * 8;

    stage_tile(A,  arow0, K, 0, As, wave, lane);
    stage_tile(Bm, brow0, K, 0, Bs, wave, lane);

    for (int i = 0; i < KITERS; ++i) {
        // own stage(i) loads done, then barrier -> all waves' stage(i) visible;
        // also guarantees everyone finished reading buf((i+1)&1) in iter i-1.
        asm volatile("s_waitcnt vmcnt(0)\n\ts_barrier" ::: "memory");
        const bf16_t* ap = As + (i & 1) * TILE_E;
        const bf16_t* bp = Bs + (i & 1) * TILE_E;
        bf16x8 af[4], bfr[4];
#pragma unroll
        for (int t = 0; t < 4; t++) {
            af[t]  = *(const bf16x8*)(ap + (wm * 64 + t * 16 + l15) * 32 + swz);
            bfr[t] = *(const bf16x8*)(bp + (wn * 64 + t * 16 + l15) * 32 + swz);
        }
        if (i + 1 < KITERS) {   // prefetch stage(i+1) into the other buffer
            stage_tile(A,  arow0, K, (i + 1) * 32, As + ((i + 1) & 1) * TILE_E, wave, lane);
            stage_tile(Bm, brow0, K, (i + 1) * 32, Bs + ((i + 1) & 1) * TILE_E, wave, lane);
        }
#pragma unroll
        for (int t = 0; t < 4; t++)
#pragma unroll
            for (int j = 0; j < 4; j++)
                acc[t][j] = __builtin_amdgcn_mfma_f32_16x16x32_bf16(
                    af[t], bfr[j], acc[t][j], 0, 0, 0);
    }
}

// ---------------- fused GEMM1+2 + elementwise epilogue (bf16 a,u out) -------
__global__ __launch_bounds__(256)
void k_gemm_fused(const bf16_t* __restrict__ A, const bf16_t* __restrict__ Wcat,
                  const float* __restrict__ x, const float* __restrict__ b_dt,
                  const float* __restrict__ negA,
                  unsigned short* __restrict__ abuf, unsigned short* __restrict__ ubuf) {
    __shared__ __align__(16) bf16_t As[2 * TILE_E];
    __shared__ __align__(16) bf16_t Bs[2 * TILE_E];

    const int tid  = threadIdx.x;
    const int lane = tid & 63;
    const int wave = tid >> 6;
    const int wm   = wave >> 1;
    const int wn   = wave & 1;
    int flat = blockIdx.y * gridDim.x + blockIdx.x;
    int bm = flat % NBM;            // consecutive blocks share bn -> B tile L2-hot
    int bn = flat / NBM;

    f32x4 acc[4][4];
#pragma unroll
    for (int i = 0; i < 4; i++)
#pragma unroll
        for (int j = 0; j < 4; j++) acc[i][j] = (f32x4){0.f, 0.f, 0.f, 0.f};

    gemm_main<DIM / 32>(A, Wcat, DIM, (long)bm * 128, (long)bn * 128,
                        As, Bs, acc, wave, lane, wm, wn);

    const int l15  = lane & 15;
    const int quad = lane >> 4;
    const int odd  = l15 & 1;
#pragma unroll
    for (int i = 0; i < 4; i++) {
#pragma unroll
        for (int j = 0; j < 4; j++) {
#pragma unroll
            for (int r = 0; r < 4; r++) {
                float v = acc[i][j][r];
                float w = __shfl_xor(v, 1);
                float dtpre = odd ? w : v;
                float bpv   = odd ? v : w;
                long row = (long)bm * 128 + wm * 64 + i * 16 + quad * 4 + r;
                int  col = bn * 128 + wn * 64 + j * 16 + l15;
                int  n   = col >> 1;
                float z  = dtpre + b_dt[n];
                float dt = (z > 15.f) ? z : __logf(1.f + __expf(z)); // softplus
                float a  = __expf(negA[n] * dt);                     // A_bar
                float u  = dt * bpv * x[row * DIM + n];              // dt*Bp*x
                long idx = row * DIM + n;
                if (odd) ubuf[idx] = f2bf_rne(u); else abuf[idx] = f2bf_rne(a);
            }
        }
    }
}

// ---------------- plain NT-GEMM: out = h*W_C^T + skip*x ----------------
__global__ __launch_bounds__(256)
void k_gemm_bt(const bf16_t* __restrict__ A, const bf16_t* __restrict__ Bm,
               float* __restrict__ C, int N, int K,
               const float* __restrict__ skip, const float* __restrict__ xres) {
    __shared__ __align__(16) bf16_t As[2 * TILE_E];
    __shared__ __align__(16) bf16_t Bs[2 * TILE_E];

    const int tid  = threadIdx.x;
    const int lane = tid & 63;
    const int wave = tid >> 6;
    const int wm   = wave >> 1;
    const int wn   = wave & 1;
    int flat = blockIdx.y * gridDim.x + blockIdx.x;
    int bm = flat % NBM;
    int bn = flat / NBM;

    f32x4 acc[4][4];
#pragma unroll
    for (int i = 0; i < 4; i++)
#pragma unroll
        for (int j = 0; j < 4; j++) acc[i][j] = (f32x4){0.f, 0.f, 0.f, 0.f};

    gemm_main<DIM / 32>(A, Bm, K, (long)bm * 128, (long)bn * 128,
                        As, Bs, acc, wave, lane, wm, wn);

    const int l15  = lane & 15;
    const int quad = lane >> 4;
#pragma unroll
    for (int i = 0; i < 4; i++) {
#pragma unroll
        for (int j = 0; j < 4; j++) {
#pragma unroll
            for (int r = 0; r < 4; r++) {
                long row = (long)bm * 128 + wm * 64 + i * 16 + quad * 4 + r;
                long col = (long)bn * 128 + wn * 64 + j * 16 + l15;
                long idx = row * (long)N + col;
                float v = acc[i][j][r];
                if (skip) v += skip[col] * xres[idx];
                C[idx] = v;
            }
        }
    }
}

// ---------------- chunked scan on bf16 a,u (2 channels per thread) ----------
// phase1: per (b,chunk,n): P = prod a, V = local scan end value
__global__ void k_scan1(const unsigned short* __restrict__ a,
                        const unsigned short* __restrict__ u,
                        float* __restrict__ P, float* __restrict__ V) {
    int t  = blockIdx.x * blockDim.x + threadIdx.x;   // [b][c][n/2], 131072
    int n2 = t & (DIM / 2 - 1);
    int c  = (t >> 10) & (CHUNKS - 1);
    int b  = t >> 15;
    long base = ((long)b * SEQ + (long)c * CLEN) * DIM + n2 * 2;
    float p0 = 1.f, v0 = 0.f, p1 = 1.f, v1 = 0.f;
    for (int s = 0; s < CLEN; s++) {
        u16x2 av = *(const u16x2*)(a + base + (long)s * DIM);
        u16x2 uv = *(const u16x2*)(u + base + (long)s * DIM);
        float a0 = bf2f(av[0]), a1 = bf2f(av[1]);
        v0 = a0 * v0 + bf2f(uv[0]);  p0 *= a0;
        v1 = a1 * v1 + bf2f(uv[1]);  p1 *= a1;
    }
    long pidx = ((long)b * CHUNKS + c) * DIM + n2 * 2;
    *(float2*)(P + pidx) = make_float2(p0, p1);
    *(float2*)(V + pidx) = make_float2(v0, v1);
}

// phase2: per (b,n): sequential scan over chunk carries (fp32)
__global__ void k_scan2(const float* __restrict__ P, const float* __restrict__ V,
                        float* __restrict__ carry) {
    int t = blockIdx.x * blockDim.x + threadIdx.x;   // B*N
    int n = t & (DIM - 1);
    int b = t >> 11;
    float H = 0.f;
    for (int c = 0; c < CHUNKS; c++) {
        long idx = ((long)b * CHUNKS + c) * DIM + n;
        carry[idx] = H;
        H = P[idx] * H + V[idx];
    }
}

// phase3: replay chunk with true initial state; emit h as bf16
__global__ void k_scan3(const unsigned short* __restrict__ a,
                        const unsigned short* __restrict__ u,
                        const float* __restrict__ carry,
                        unsigned short* __restrict__ h) {
    int t  = blockIdx.x * blockDim.x + threadIdx.x;
    int n2 = t & (DIM / 2 - 1);
    int c  = (t >> 10) & (CHUNKS - 1);
    int b  = t >> 15;
    long base = ((long)b * SEQ + (long)c * CLEN) * DIM + n2 * 2;
    long cidx = ((long)b * CHUNKS + c) * DIM + n2 * 2;
    float2 Hc = *(const float2*)(carry + cidx);
    float H0 = Hc.x, H1 = Hc.y;
    for (int s = 0; s < CLEN; s++) {
        u16x2 av = *(const u16x2*)(a + base + (long)s * DIM);
        u16x2 uv = *(const u16x2*)(u + base + (long)s * DIM);
        H0 = bf2f(av[0]) * H0 + bf2f(uv[0]);
        H1 = bf2f(av[1]) * H1 + bf2f(uv[1]);
        u16x2 o; o[0] = f2bf_rne(H0); o[1] = f2bf_rne(H1);
        *(u16x2*)(h + base + (long)s * DIM) = o;
    }
}

extern "C" void kernel_launch(void* const* d_in, const int* in_sizes, int n_in,
                              void* d_out, int out_size, void* d_ws, size_t ws_size,
                              hipStream_t stream) {
    const float* x      = (const float*)d_in[0];
    const float* W_dt   = (const float*)d_in[1];
    const float* b_dt   = (const float*)d_in[2];
    const float* W_B    = (const float*)d_in[3];
    const float* W_C    = (const float*)d_in[4];
    const float* A_log  = (const float*)d_in[5];
    const float* D_skip = (const float*)d_in[6];
    float* out = (float*)d_out;

    char* ws = (char*)d_ws;
    size_t off = 0;
    auto alloc = [&](size_t bytes) -> char* {
        char* p = ws + off;
        off += (bytes + 255) & ~(size_t)255;
        return p;
    };
    unsigned short* xb   = (unsigned short*)alloc((size_t)MTOT * DIM * 2); // reused as h_bf
    unsigned short* wcat = (unsigned short*)alloc((size_t)2 * DIM * DIM * 2);
    unsigned short* wcb  = (unsigned short*)alloc((size_t)DIM * DIM * 2);
    unsigned short* abuf = (unsigned short*)alloc((size_t)MTOT * DIM * 2);  // bf16 a
    unsigned short* ubuf = (unsigned short*)alloc((size_t)MTOT * DIM * 2);  // bf16 u
    float* P     = (float*)alloc((size_t)NBATCH * CHUNKS * DIM * 4);
    float* V     = (float*)alloc((size_t)NBATCH * CHUNKS * DIM * 4);
    float* carry = (float*)alloc((size_t)NBATCH * CHUNKS * DIM * 4);
    float* negA  = (float*)alloc((size_t)DIM * 4);

    const int n4x = MTOT * DIM / 4;
    const int n4w = DIM * DIM / 4;
    k_convert<<<n4x / 256, 256, 0, stream>>>(x, xb, n4x);
    k_convert_ilv<<<n4w / 256, 256, 0, stream>>>(W_dt, wcat, n4w, 0);
    k_convert_ilv<<<n4w / 256, 256, 0, stream>>>(W_B,  wcat, n4w, 1);
    k_convert<<<n4w / 256, 256, 0, stream>>>(W_C, wcb, n4w);
    k_prep_a<<<DIM / 256, 256, 0, stream>>>(A_log, negA, DIM);

    // fused GEMM1+2 + elementwise: M=8192, N=4096, K=2048
    dim3 fgrid(2 * DIM / 128, MTOT / 128);
    k_gemm_fused<<<fgrid, 256, 0, stream>>>((const bf16_t*)xb, (const bf16_t*)wcat,
                                            x, b_dt, negA, abuf, ubuf);

    const int scan2_threads = NBATCH * CHUNKS * DIM / 2;   // 131072
    k_scan1<<<scan2_threads / 256, 256, 0, stream>>>(abuf, ubuf, P, V);
    k_scan2<<<(NBATCH * DIM) / 256, 256, 0, stream>>>(P, V, carry);
    k_scan3<<<scan2_threads / 256, 256, 0, stream>>>(abuf, ubuf, carry, xb /* h_bf */);

    // out = h * W_C^T + D_skip * x
    dim3 ggrid(DIM / 128, MTOT / 128);
    k_gemm_bt<<<ggrid, 256, 0, stream>>>((const bf16_t*)xb, (const bf16_t*)wcb,
                                         out, DIM, DIM, D_skip, x);
}